// Round 5
// baseline (186.204 us; speedup 1.0000x reference)
//
#include <hip/hip_runtime.h>
#include <stdint.h>

// Sampler: B=128 rows, V=128000 vocab, K=20.
// Outputs (float32, concat): sampled[B], topk_logprobs[B*K], topk_indices[B*K].
//
// k1 (B*16 blocks x 256): streams 2 float4-pairs/iter with depth-2 prefetch
//     (named scalars only -- register arrays spill, round-3 lesson).
//     exp2-domain sum: s = sum 2^(x*c), c = inv_t*log2e (== sum e^(x/t)).
//     Gumbel in RATIO domain: incumbent G = e/q, screen `e > 0.999*G*(1-u)`
//     (valid since -ln u >= 1-u) -- 3 cheap VALU ops, no transcendental,
//     self-seeding from G=0, exact eval (accurate q, IEEE div) only on passers.
//     top-K candidates via x >= TAU=3.0 -> rare LDS push.
// k2 (B blocks x 64): merges wave records, parallel candidate gather, exact
//     top-K selection; exact full-rescan fallback if <K candidates/overflow.

#define KMAX 20
#define SAMPLING_EPS 1e-5f
#define TAU 3.0f
#define CPB 64
#define LOG2E 1.44269504f
#define NSPLIT 16

static __device__ __forceinline__ unsigned int ord32(float v) {
    unsigned int u = __float_as_uint(v);
    return u ^ ((unsigned int)((int)u >> 31) | 0x80000000u);
}
static __device__ __forceinline__ float unord32(unsigned int x) {
    unsigned int u = (x & 0x80000000u) ? (x ^ 0x80000000u) : ~x;
    return __uint_as_float(u);
}
static __device__ __forceinline__ unsigned long long shflxor64(unsigned long long v, int off) {
    int lo = __shfl_xor((int)(unsigned int)v, off, 64);
    int hi = __shfl_xor((int)(unsigned int)(v >> 32), off, 64);
    return ((unsigned long long)(unsigned int)hi << 32) | (unsigned int)lo;
}

__global__ __launch_bounds__(256, 8) void k1_partials(
        const float* __restrict__ logits, const float* __restrict__ u,
        const float* __restrict__ temp,
        unsigned int* __restrict__ wrec,     // per-wave {s, G, gcol, pad}
        unsigned int* __restrict__ cntbuf,   // per-block raw candidate count
        uint2* __restrict__ candbuf,         // per-block CPB {val_bits, col}
        int V) {
    __shared__ int cnt;
    __shared__ uint2 cand[CPB];
    const int b = blockIdx.x;
    const int r = b / NSPLIT;
    const int sp = b - r * NSPLIT;
    const int t = threadIdx.x;
    const int lane = t & 63;
    const int w = t >> 6;
    if (t == 0) cnt = 0;
    __syncthreads();

    const float traw = temp[r];
    const bool greedy = traw < SAMPLING_EPS;
    const float c = (greedy ? 1.0f : (1.0f / traw)) * LOG2E;

    const int nf4 = V >> 2;
    const int per = (nf4 + NSPLIT - 1) / NSPLIT;
    const int f0 = sp * per;
    const int f1 = min(f0 + per, nf4);
    const int f1m = f1 - 1;

    const float4* __restrict__ l4 = (const float4*)(logits + (size_t)r * V);
    const float4* __restrict__ u4 = (const float4*)(u + (size_t)r * V);

    float s = 0.0f;
    float G = 0.0f, Gs = 0.0f;   // incumbent gumbel ratio e/q, screen copy
    int gcol = 0;

    #define PUSH_CAND(x_, col_)  do { \
        const int idx_ = atomicAdd(&cnt, 1); \
        if (idx_ < CPB) cand[idx_] = make_uint2(__float_as_uint(x_), (unsigned)(col_)); \
    } while (0)

    if (greedy) {
        // common path per f4: 4 mul + 4 exp + 4 add + 3 max + 1 cmp + 1 branch
        #define GPROC4(lv_, colb_, act_) do { \
            const float x0 = (act_) ? (lv_).x : -INFINITY; \
            const float x1 = (act_) ? (lv_).y : -INFINITY; \
            const float x2 = (act_) ? (lv_).z : -INFINITY; \
            const float x3 = (act_) ? (lv_).w : -INFINITY; \
            s += exp2f(x0 * c); s += exp2f(x1 * c); \
            s += exp2f(x2 * c); s += exp2f(x3 * c); \
            const float xm = fmaxf(fmaxf(x0, x1), fmaxf(x2, x3)); \
            if (xm >= TAU) { \
                if (x0 >= TAU) PUSH_CAND(x0, (colb_)); \
                if (x1 >= TAU) PUSH_CAND(x1, (colb_) + 1); \
                if (x2 >= TAU) PUSH_CAND(x2, (colb_) + 2); \
                if (x3 >= TAU) PUSH_CAND(x3, (colb_) + 3); \
            } \
        } while (0)
        int p = f0 + t;
        if (p < f1) {
            float4 la = l4[p];
            float4 lb = l4[min(p + 256, f1m)];
            for (;;) {
                const int pn = p + 512;
                const float4 nla = l4[min(pn, f1m)];
                const float4 nlb = l4[min(pn + 256, f1m)];
                GPROC4(la, p << 2, true);
                GPROC4(lb, (p + 256) << 2, (p + 256) < f1);
                if (pn >= f1) break;
                p = pn; la = nla; lb = nlb;
            }
        }
        #undef GPROC4
    } else {
        // common path per f4: 4 mul + 4 exp + 4 add + 4 sub + 4 mul + 4 cmp
        //                     + 3 max + 1 cmp + OR-chain + 1 branch
        #define MPROC4(lv_, uv_, colb_, act_) do { \
            const float x0 = (act_) ? (lv_).x : -INFINITY; \
            const float x1 = (act_) ? (lv_).y : -INFINITY; \
            const float x2 = (act_) ? (lv_).z : -INFINITY; \
            const float x3 = (act_) ? (lv_).w : -INFINITY; \
            const float e0 = exp2f(x0 * c), e1 = exp2f(x1 * c); \
            const float e2 = exp2f(x2 * c), e3 = exp2f(x3 * c); \
            s += e0; s += e1; s += e2; s += e3; \
            const float wm0 = 1.0f - (uv_).x, wm1 = 1.0f - (uv_).y; \
            const float wm2 = 1.0f - (uv_).z, wm3 = 1.0f - (uv_).w; \
            const bool b0 = e0 > Gs * wm0, b1 = e1 > Gs * wm1; \
            const bool b2 = e2 > Gs * wm2, b3 = e3 > Gs * wm3; \
            const float xm = fmaxf(fmaxf(x0, x1), fmaxf(x2, x3)); \
            if (b0 | b1 | b2 | b3 | (xm >= TAU)) { \
                if (x0 >= TAU) PUSH_CAND(x0, (colb_)); \
                if (x1 >= TAU) PUSH_CAND(x1, (colb_) + 1); \
                if (x2 >= TAU) PUSH_CAND(x2, (colb_) + 2); \
                if (x3 >= TAU) PUSH_CAND(x3, (colb_) + 3); \
                if (b0) { \
                    const float uu = (uv_).x; \
                    const float q = (uu > 0.984375f) ? -log1pf(-wm0) : -__logf(uu); \
                    const float rr = e0 / q; \
                    if (rr > G) { G = rr; Gs = G * 0.99902344f; gcol = (colb_); } \
                } \
                if (b1) { \
                    const float uu = (uv_).y; \
                    const float q = (uu > 0.984375f) ? -log1pf(-wm1) : -__logf(uu); \
                    const float rr = e1 / q; \
                    if (rr > G) { G = rr; Gs = G * 0.99902344f; gcol = (colb_) + 1; } \
                } \
                if (b2) { \
                    const float uu = (uv_).z; \
                    const float q = (uu > 0.984375f) ? -log1pf(-wm2) : -__logf(uu); \
                    const float rr = e2 / q; \
                    if (rr > G) { G = rr; Gs = G * 0.99902344f; gcol = (colb_) + 2; } \
                } \
                if (b3) { \
                    const float uu = (uv_).w; \
                    const float q = (uu > 0.984375f) ? -log1pf(-wm3) : -__logf(uu); \
                    const float rr = e3 / q; \
                    if (rr > G) { G = rr; Gs = G * 0.99902344f; gcol = (colb_) + 3; } \
                } \
            } \
        } while (0)
        int p = f0 + t;
        if (p < f1) {
            const int pb0 = min(p + 256, f1m);
            float4 la = l4[p],   ua = u4[p];
            float4 lb = l4[pb0], ub = u4[pb0];
            for (;;) {
                const int pn = p + 512;
                const int pnc = min(pn, f1m);
                const int pnb = min(pn + 256, f1m);
                const float4 nla = l4[pnc], nlb = l4[pnb];
                const float4 nua = u4[pnc], nub = u4[pnb];
                MPROC4(la, ua, p << 2, true);
                MPROC4(lb, ub, (p + 256) << 2, (p + 256) < f1);
                if (pn >= f1) break;
                p = pn; la = nla; lb = nlb; ua = nua; ub = nub;
            }
        }
        #undef MPROC4
    }
    #undef PUSH_CAND

    // wave reductions: s sum; gumbel ratio-key max (ratio desc, col asc)
    #pragma unroll
    for (int off = 1; off < 64; off <<= 1) s += __shfl_xor(s, off, 64);
    unsigned long long gk = greedy ? 0ull
        : (((unsigned long long)ord32(G) << 32) | (unsigned int)~(unsigned int)gcol);
    #pragma unroll
    for (int off = 1; off < 64; off <<= 1) {
        const unsigned long long o = shflxor64(gk, off);
        gk = (o > gk) ? o : gk;
    }
    if (lane == 0) {
        unsigned int* rp = wrec + (size_t)(b * 4 + w) * 4;
        rp[0] = __float_as_uint(s);
        rp[1] = __float_as_uint(unord32((unsigned int)(gk >> 32)));
        rp[2] = ~(unsigned int)gk;
        rp[3] = 0u;
    }
    __syncthreads();
    const int cfin = cnt;
    if (t == 0) cntbuf[b] = (unsigned)cfin;
    if (t < min(cfin, CPB)) candbuf[(size_t)b * CPB + t] = cand[t];
}

__global__ __launch_bounds__(64) void k2_finalize(
        const unsigned int* __restrict__ wrec, const unsigned int* __restrict__ cntbuf,
        const uint2* __restrict__ candbuf, const float* __restrict__ logits,
        const float* __restrict__ temp, float* __restrict__ out,
        int B, int V, int K) {
    __shared__ unsigned long long kbuf[512];
    const int r = blockIdx.x;
    const int lane = threadIdx.x;
    const int NW = NSPLIT * 4;

    const float traw = temp[r];
    const bool greedy = traw < SAMPLING_EPS;
    const float tt = greedy ? 1.0f : traw;

    float s = 0.0f;
    unsigned long long gk = 0ull;
    if (lane < NW) {
        const uint4 rv = ((const uint4*)wrec)[(size_t)r * NW + lane];
        s = __uint_as_float(rv.x);
        gk = ((unsigned long long)ord32(__uint_as_float(rv.y)) << 32) | (unsigned int)~rv.z;
    }
    #pragma unroll
    for (int off = 1; off < 64; off <<= 1) s += __shfl_xor(s, off, 64);
    #pragma unroll
    for (int off = 1; off < 64; off <<= 1) {
        const unsigned long long o = shflxor64(gk, off);
        gk = (o > gk) ? o : gk;
    }
    const float lS = logf(s);

    const int cnt_raw = (lane < NSPLIT) ? (int)cntbuf[r * NSPLIT + lane] : 0;
    const int myc = min(cnt_raw, CPB);
    const bool ovf = __ballot(cnt_raw > CPB) != 0ull;
    int incl = myc;
    #pragma unroll
    for (int d = 1; d < 64; d <<= 1) {
        const int o = __shfl_up(incl, d, 64);
        if (lane >= d) incl += o;
    }
    const int T = __shfl(incl, 63, 64);

    // parallel gather: 4 lanes per source block
    const int rec = lane >> 2;
    const int sl0 = lane & 3;
    if (rec < NSPLIT) {
        const int cbase = __shfl(incl - myc, rec, 64);
        const int ccnt  = __shfl(myc, rec, 64);
        const uint2* cb = candbuf + (size_t)(r * NSPLIT + rec) * CPB;
        for (int i = sl0; i < ccnt; i += 4) {
            if (cbase + i < 512) {
                const uint2 e = cb[i];
                kbuf[cbase + i] = ((unsigned long long)ord32(__uint_as_float(e.x)) << 32)
                                | (unsigned int)~e.y;
            }
        }
    }
    __syncthreads();

    unsigned long long keys[8];
    #pragma unroll
    for (int jj = 0; jj < 8; ++jj) keys[jj] = 0ull;

    if (!ovf && T >= K && T <= 512) {
        #pragma unroll
        for (int jj = 0; jj < 8; ++jj) {
            const int idx = lane + 64 * jj;
            if (idx < T) keys[jj] = kbuf[idx];
        }
    } else {
        // exact fallback: wave-cooperative top-K full rescan (insurance)
        unsigned long long mykey = ((unsigned long long)0x007FFFFFu) << 32;
        unsigned long long minkey = mykey;
        float vmin = -INFINITY;
        const float* lr = logits + (size_t)r * V;
        for (int base = 0; base < V; base += 64) {
            const int i = base + lane;
            const float x = (i < V) ? lr[i] : -INFINITY;
            unsigned long long cm = __ballot((i < V) && (x >= vmin));
            while (cm) {
                const int src = (int)__builtin_ctzll(cm);
                cm &= cm - 1;
                const float cv = __shfl(x, src, 64);
                const int cc = __shfl(i, src, 64);
                const unsigned long long ck =
                    ((unsigned long long)ord32(cv) << 32) | (unsigned int)~(unsigned int)cc;
                if (ck > minkey) {
                    const bool own = (lane < K) && (mykey == minkey);
                    const unsigned long long om = __ballot(own);
                    if (lane == (int)__builtin_ctzll(om)) mykey = ck;
                    unsigned long long mk = (lane < K) ? mykey : ~0ull;
                    #pragma unroll
                    for (int o2 = 1; o2 < 64; o2 <<= 1) {
                        const unsigned long long o = shflxor64(mk, o2);
                        mk = (o < mk) ? o : mk;
                    }
                    minkey = mk;
                    vmin = unord32((unsigned int)(mk >> 32));
                }
            }
        }
        keys[0] = (lane < K) ? mykey : 0ull;
    }

    float* out_s  = out;
    float* out_lp = out + B;
    float* out_ix = out + B + (size_t)B * K;

    unsigned int top1 = 0;
    for (int k = 0; k < K; ++k) {
        unsigned long long loc = keys[0];
        #pragma unroll
        for (int jj = 1; jj < 8; ++jj) loc = (keys[jj] > loc) ? keys[jj] : loc;
        #pragma unroll
        for (int off = 1; off < 64; off <<= 1) {
            const unsigned long long o = shflxor64(loc, off);
            loc = (o > loc) ? o : loc;
        }
        #pragma unroll
        for (int jj = 0; jj < 8; ++jj) if (keys[jj] == loc) keys[jj] = 0ull;
        if (lane == 0) {
            const unsigned int col = ~(unsigned int)loc;
            const float v = unord32((unsigned int)(loc >> 32));
            out_lp[(size_t)r * K + k] = v / tt - lS;   // IEEE div matches ref's scaled
            out_ix[(size_t)r * K + k] = (float)col;
            if (k == 0) top1 = col;
        }
    }
    if (lane == 0) {
        out_s[r] = (float)(greedy ? top1 : (~(unsigned int)gk));
    }
}

extern "C" void kernel_launch(void* const* d_in, const int* in_sizes, int n_in,
                              void* d_out, int out_size, void* d_ws, size_t ws_size,
                              hipStream_t stream) {
    const float* logits = (const float*)d_in[0];
    const float* temp   = (const float*)d_in[1];
    const float* u      = (const float*)d_in[2];
    const int B = in_sizes[1];
    const int V = in_sizes[0] / B;
    int K = (out_size - B) / (2 * B);
    if (K > KMAX) K = KMAX;
    if (K < 1) K = 1;

    const int blocks = B * NSPLIT;
    unsigned int* wrec   = (unsigned int*)d_ws;              // blocks*4 waves * 4 u32
    unsigned int* cntbuf = wrec + (size_t)blocks * 16;       // blocks u32
    uint2*        candbf = (uint2*)(cntbuf + blocks);        // blocks * CPB uint2

    k1_partials<<<dim3(blocks), dim3(256), 0, stream>>>(
        logits, u, temp, wrec, cntbuf, candbf, V);
    k2_finalize<<<dim3(B), dim3(64), 0, stream>>>(
        wrec, cntbuf, candbf, logits, temp, (float*)d_out, B, V, K);
}